// Round 12
// baseline (255.425 us; speedup 1.0000x reference)
//
#include <hip/hip_runtime.h>
#include <stdint.h>

// MHA fused: qkv-proj (32x32 MFMA GEMM, 64-row-period swizzle) -> causal flash
// attn -> out-proj (16x16 MFMA, r10-proven).  B=2, S=2048, H=2048, heads=16, D=128.
// Round-12: out-proj reverted to r10 16x16 (32x32 regressed it ~13us);
// QKV keeps 32x32 but swizzle widened to kill the 12.7M bank conflicts.

using bf16x8 = __attribute__((ext_vector_type(8))) __bf16;
using f32x4  = __attribute__((ext_vector_type(4))) float;
using f32x16 = __attribute__((ext_vector_type(16))) float;

#define S_LEN 2048
#define HID   2048
#define NHEAD 16
#define DHEAD 128
#define KDIM  2048
// 1/sqrt(128) * log2(e): attention softmax runs in exp2 domain
#define QSCALE_L2E (0.08838834764831845f * 1.4426950408889634f)

__device__ __forceinline__ unsigned short f2bf(float f) {
  union { float f; unsigned int u; } c; c.f = f;
  unsigned int u = c.u;
  return (unsigned short)((u + 0x7FFFu + ((u >> 16) & 1u)) >> 16);  // RNE
}

__device__ __forceinline__ unsigned int pkbf(float a, float b) {
  union { __bf16 h[2]; unsigned int u; } x;
  x.h[0] = (__bf16)a; x.h[1] = (__bf16)b;
  return x.u;
}

__device__ __forceinline__ void gload_lds16(const void* g, void* l) {
  __builtin_amdgcn_global_load_lds(
      (const __attribute__((address_space(1))) unsigned int*)g,
      (__attribute__((address_space(3))) unsigned int*)l, 16, 0, 0);
}

__device__ __forceinline__ f32x4 mfma16(bf16x8 a, bf16x8 b, f32x4 c) {
  return __builtin_amdgcn_mfma_f32_16x16x32_bf16(a, b, c, 0, 0, 0);
}

__device__ __forceinline__ f32x16 mfma32(bf16x8 a, bf16x8 b, f32x16 c) {
  return __builtin_amdgcn_mfma_f32_32x32x16_bf16(a, b, c, 0, 0, 0);
}

__device__ __forceinline__ float hmax4(f32x4 v) {
  return fmaxf(fmaxf(v[0], v[1]), fmaxf(v[2], v[3]));
}

// 64-row-period swizzle for 128B LDS rows: rows 8/16/24 apart get distinct slots.
__device__ __forceinline__ int swz64(int r) {
  return (((r & 7) ^ ((r >> 3) & 7)) << 4);
}

// merged conversion: x -> xb, Wqkv -> Wqkvb in one launch
__global__ void cvt_two(const float* __restrict__ a, unsigned short* __restrict__ ao, int na4,
                        const float* __restrict__ b, unsigned short* __restrict__ bo, int nb4) {
  const int stride = gridDim.x * blockDim.x;
  const int tot = na4 + nb4;
  for (int i = blockIdx.x * blockDim.x + threadIdx.x; i < tot; i += stride) {
    const float4* src; ushort4* dst; int idx;
    if (i < na4) { src = (const float4*)a; dst = (ushort4*)ao; idx = i; }
    else         { src = (const float4*)b; dst = (ushort4*)bo; idx = i - na4; }
    float4 v = src[idx];
    ushort4 o;
    o.x = f2bf(v.x); o.y = f2bf(v.y); o.z = f2bf(v.z); o.w = f2bf(v.w);
    dst[idx] = o;
  }
}

// ============================================================================
// QKV GEMM: C(4096 x 6144) = A * Wqkv^T + b -> scatter to Q/K/Vt (bf16).
// 128x128 tile, BK=64, 4 waves (2x2 of 64x64), 32x32x16 MFMA (acc 2x2 f32x16).
// A/B frag: lane holds row (l&31), k-slice (l>>5)*8 of each K=16 step.
// C/D: col = lane&31, row = (reg&3) + 8*(reg>>2) + 4*(lane>>5)  [m74/m101].
// K-loop LDS uses swz64 (64-row period) on BOTH pre-swizzled global source and
// ds_read address -> same data, conflict-free for the 32-row read pattern.
// ============================================================================
__global__ __launch_bounds__(256) void gemm_qkv(
    const unsigned short* __restrict__ A, const unsigned short* __restrict__ Bw,
    const float* __restrict__ bias,
    unsigned short* __restrict__ q_out, unsigned short* __restrict__ k_out,
    unsigned short* __restrict__ vt_out)
{
  constexpr int K = KDIM;
  __shared__ __align__(16) char lds[32768];
  char* lsA = lds;            // [128 rows][64 bf16], swz64 within row
  char* lsB = lds + 16384;
  const int tid = threadIdx.x;
  const int l = tid & 63, w = tid >> 6;
  const int wr = w >> 1, wc = w & 1;
  const int bm = blockIdx.x * 128, bn = blockIdx.y * 128;
  const int l31 = l & 31, hi = l >> 5;

  f32x16 acc[2][2] = {};

  for (int k0 = 0; k0 < K; k0 += 64) {
    #pragma unroll
    for (int c = 0; c < 4; ++c) {
      const int o = c * 4096 + tid * 16;
      const int r = o >> 7;
      const int cb = (o & 127) ^ swz64(r);
      gload_lds16((const char*)A + ((size_t)(bm + r) * K + k0) * 2 + cb,
                  lsA + c * 4096 + (w << 10));
      gload_lds16((const char*)Bw + ((size_t)(bn + r) * K + k0) * 2 + cb,
                  lsB + c * 4096 + (w << 10));
    }
    __syncthreads();

    #pragma unroll
    for (int ks = 0; ks < 4; ++ks) {
      bf16x8 af[2], bfr[2];
      const int co = ks * 32 + hi * 16;
      #pragma unroll
      for (int s = 0; s < 2; ++s) {
        const int ra = wr * 64 + s * 32 + l31;
        af[s]  = *(const bf16x8*)(lsA + ra * 128 + (co ^ swz64(ra)));
        const int rb = wc * 64 + s * 32 + l31;
        bfr[s] = *(const bf16x8*)(lsB + rb * 128 + (co ^ swz64(rb)));
      }
      acc[0][0] = mfma32(af[0], bfr[0], acc[0][0]);
      acc[0][1] = mfma32(af[0], bfr[1], acc[0][1]);
      acc[1][0] = mfma32(af[1], bfr[0], acc[1][0]);
      acc[1][1] = mfma32(af[1], bfr[1], acc[1][1]);
    }
    __syncthreads();   // also frees lds for the epilogue staging below
  }

  float bv[2];
  #pragma unroll
  for (int sj = 0; sj < 2; ++sj) bv[sj] = bias[bn + wc * 64 + sj * 32 + l31];

  // QKV scatter via LDS staging (coalesced 16B stores); block covers one (sec,head,b)
  const int secb  = bn >> 11;            // 0=Q 1=K 2=V (constant per block)
  const int headb = (bn & 2047) >> 7;
  const int s0    = bm & 2047;
  const int bh    = (bm >> 11) * NHEAD + headb;

  if (secb < 2) {
    // LDS [s 128][d 128] bf16, row-swizzled
    #pragma unroll
    for (int si = 0; si < 2; ++si) {
      #pragma unroll
      for (int sj = 0; sj < 2; ++sj) {
        const int col = wc * 64 + sj * 32 + l31;
        #pragma unroll
        for (int e = 0; e < 16; ++e) {
          const int rr = wr * 64 + si * 32 + (e & 3) + 8 * (e >> 2) + 4 * hi;
          float v = acc[si][sj][e] + bv[sj];
          if (secb == 0) v *= QSCALE_L2E;
          *(unsigned short*)(lds + rr * 256 + ((col * 2) ^ ((rr & 7) << 4))) = f2bf(v);
        }
      }
    }
    __syncthreads();
    unsigned short* qk = (secb == 0) ? q_out : k_out;
    char* gbase = (char*)(qk + ((size_t)bh * S_LEN + s0) * DHEAD);
    #pragma unroll
    for (int it = 0; it < 8; ++it) {
      const int o = it * 4096 + tid * 16;
      const int s = o >> 8, db = o & 255;
      uint4 v = *(const uint4*)(lds + s * 256 + (db ^ ((s & 7) << 4)));
      *(uint4*)(gbase + (size_t)s * 256 + db) = v;
    }
  } else {
    // Vt: LDS [d 128][s 128] bf16; regs 4g..4g+3 are 4 consecutive s -> uint2
    #pragma unroll
    for (int si = 0; si < 2; ++si) {
      #pragma unroll
      for (int sj = 0; sj < 2; ++sj) {
        const int d = wc * 64 + sj * 32 + l31;
        #pragma unroll
        for (int g = 0; g < 4; ++g) {
          const int sb = wr * 64 + si * 32 + 8 * g + 4 * hi;
          uint2 pw;
          pw.x = pkbf(acc[si][sj][4 * g] + bv[sj],     acc[si][sj][4 * g + 1] + bv[sj]);
          pw.y = pkbf(acc[si][sj][4 * g + 2] + bv[sj], acc[si][sj][4 * g + 3] + bv[sj]);
          *(uint2*)(lds + d * 256 + ((sb * 2) ^ ((d & 7) << 4))) = pw;
        }
      }
    }
    __syncthreads();
    char* gbase = (char*)vt_out + ((size_t)bh * DHEAD) * (S_LEN * 2) + (size_t)s0 * 2;
    #pragma unroll
    for (int it = 0; it < 8; ++it) {
      const int o = it * 4096 + tid * 16;
      const int d = o >> 8, sb = o & 255;
      uint4 v = *(const uint4*)(lds + d * 256 + (sb ^ ((d & 7) << 4)));
      *(uint4*)(gbase + (size_t)d * (S_LEN * 2) + sb) = v;
    }
  }
}

// ============================================================================
// Out-projection: r10-proven 16x16 MFMA, 128x128 tile, LDS-staged fp32 epilogue.
// ============================================================================
__global__ __launch_bounds__(256) void gemm_out(
    const unsigned short* __restrict__ A, const unsigned short* __restrict__ Bw,
    const float* __restrict__ bias, float* __restrict__ c_out)
{
  constexpr int K = KDIM, N = HID;
  __shared__ __align__(16) char lds[32768];
  char* lsA = lds;
  char* lsB = lds + 16384;
  const int tid = threadIdx.x;
  const int l = tid & 63, w = tid >> 6;
  const int wr = w >> 1, wc = w & 1;
  const int bm = blockIdx.x * 128, bn = blockIdx.y * 128;
  const int row16 = l & 15, kg = l >> 4;

  f32x4 acc[4][4] = {};

  for (int k0 = 0; k0 < K; k0 += 64) {
    #pragma unroll
    for (int c = 0; c < 4; ++c) {
      const int o = c * 4096 + tid * 16;
      const int r = o >> 7;
      const int cb = (o & 127) ^ ((r & 7) << 4);
      gload_lds16((const char*)A + ((size_t)(bm + r) * K + k0) * 2 + cb,
                  lsA + c * 4096 + (w << 10));
      gload_lds16((const char*)Bw + ((size_t)(bn + r) * K + k0) * 2 + cb,
                  lsB + c * 4096 + (w << 10));
    }
    __syncthreads();

    #pragma unroll
    for (int h = 0; h < 2; ++h) {
      bf16x8 af[4], bfr[4];
      #pragma unroll
      for (int i = 0; i < 4; ++i) {
        const int ra = wr * 64 + i * 16 + row16;
        af[i]  = *(const bf16x8*)(lsA + ra * 128 + ((h * 64 + kg * 16) ^ ((ra & 7) << 4)));
        const int rb = wc * 64 + i * 16 + row16;
        bfr[i] = *(const bf16x8*)(lsB + rb * 128 + ((h * 64 + kg * 16) ^ ((rb & 7) << 4)));
      }
      #pragma unroll
      for (int i = 0; i < 4; ++i)
        #pragma unroll
        for (int j = 0; j < 4; ++j)
          acc[i][j] = mfma16(af[i], bfr[j], acc[i][j]);
    }
    __syncthreads();
  }

  // fp32 out: two 64-row passes through LDS [64][512B], then coalesced copy.
  #pragma unroll
  for (int p = 0; p < 2; ++p) {
    if (wr == p) {
      #pragma unroll
      for (int i = 0; i < 4; ++i) {
        #pragma unroll
        for (int j = 0; j < 4; ++j) {
          const int c = wc * 64 + j * 16 + row16;
          const float bv = bias[bn + c];
          #pragma unroll
          for (int r = 0; r < 4; ++r) {
            const int rl = i * 16 + kg * 4 + r;
            *(float*)(lds + rl * 512 + ((c * 4) ^ ((rl & 7) << 4))) = acc[i][j][r] + bv;
          }
        }
      }
    }
    __syncthreads();
    #pragma unroll
    for (int it = 0; it < 8; ++it) {
      const int o = it * 4096 + tid * 16;
      const int rw = o >> 9, cb = o & 511;
      uint4 v = *(const uint4*)(lds + rw * 512 + (cb ^ ((rw & 7) << 4)));
      *(uint4*)((char*)c_out + ((size_t)(bm + p * 64 + rw) * N + bn) * 4 + cb) = v;
    }
    __syncthreads();
  }
}

// Causal flash attention: swapped QK^T, 32 q-rows/wave, 2-phase dbuf pipeline.
// Grid: (16 q-tiles of 128 rows, 32 bh). Block: 4 waves.
__global__ __launch_bounds__(256, 2) void attn_fwd(
    const unsigned short* __restrict__ Q, const unsigned short* __restrict__ Kk,
    const unsigned short* __restrict__ Vt, unsigned short* __restrict__ O,
    const float* __restrict__ Wout, unsigned short* __restrict__ Woutb)
{
  __shared__ char lsK[2][64 * 256];    // dbuf [64 kv][128 d] bf16, XOR-swizzled
  __shared__ char lsV[2][128 * 128];   // dbuf [128 d][64 kv] bf16, XOR-swizzled
  __shared__ char lsP[4][32 * 128];    // per-wave [32 q][64 kv] bf16, XOR-swizzled
  const int tid = threadIdx.x, l = tid & 63, w = tid >> 6;
  const int row16 = l & 15, kg = l >> 4;
  const int qb = (blockIdx.y < 16) ? (15 - (int)blockIdx.x) : (int)blockIdx.x;
  const int bh = blockIdx.y;
  const int bidx = bh >> 4, head = bh & 15;

  const char* Qh = (const char*)(Q  + (size_t)bh * S_LEN * DHEAD);
  const char* Kh = (const char*)(Kk + (size_t)bh * S_LEN * DHEAD);
  const char* Vh = (const char*)(Vt + (size_t)bh * DHEAD * S_LEN);

  const int q0w = qb * 128 + w * 32;   // this wave's first q row

  bf16x8 qf[2][4];
  #pragma unroll
  for (int qs = 0; qs < 2; ++qs)
    #pragma unroll
    for (int t = 0; t < 4; ++t)
      qf[qs][t] = *(const bf16x8*)(Qh + ((size_t)(q0w + qs * 16 + row16) * DHEAD + t * 32 + kg * 8) * 2);

  float m[2]  = {-1e30f, -1e30f};
  float ls[2] = {0.f, 0.f};
  f32x4 oacc[2][8] = {};

  const int last = 2 * qb + 1;

#define STAGE(buf, kt_) do {                                                     \
    _Pragma("unroll")                                                            \
    for (int c = 0; c < 4; ++c) {                                                \
      const int o = c * 4096 + tid * 16;                                         \
      const int rk = o >> 8, cbk = (o & 255) ^ ((rk & 7) << 4);                  \
      gload_lds16(Kh + (size_t)((kt_) * 64 + rk) * 256 + cbk,                    \
                  lsK[buf] + c * 4096 + (w << 10));                              \
      const int dv = o >> 7, cbv = (o & 127) ^ ((dv & 7) << 4);                  \
      gload_lds16(Vh + (size_t)dv * 4096 + (size_t)(kt_) * 128 + cbv,            \
                  lsV[buf] + c * 4096 + (w << 10));                              \
    } } while (0)

  STAGE(0, 0);

  // ---- Wout conversion side-work (overlaps first-tile stage latency)
  {
    const int slice = (int)blockIdx.y * 16 + (int)blockIdx.x;   // 0..511
    const float4* src = (const float4*)Wout;
    ushort4* dst = (ushort4*)Woutb;
    const int base = slice * 2048;   // 512 * 2048 float4 = Wout (4M floats)
    #pragma unroll
    for (int i = 0; i < 8; ++i) {
      float4 v = src[base + i * 256 + tid];
      ushort4 o;
      o.x = f2bf(v.x); o.y = f2bf(v.y); o.z = f2bf(v.z); o.w = f2bf(v.w);
      dst[base + i * 256 + tid] = o;
    }
  }

  __syncthreads();

  int cur = 0;
  for (int kt = 0; ; ++kt) {
    if (kt < last) STAGE(cur ^ 1, kt + 1);   // prefetch next tile

    if (kt * 64 <= q0w + 31) {
      const char* Kc = lsK[cur];
      const char* Vc = lsV[cur];
      char* Pl = lsP[w];

      // ---- S^T = K Q^T
      f32x4 sc[4][2] = {};
      #pragma unroll
      for (int j = 0; j < 4; ++j) {
        const int krow = j * 16 + row16;
        const int sw = (krow & 7) << 4;
        bf16x8 kf[4];
        #pragma unroll
        for (int t = 0; t < 4; ++t)
          kf[t] = *(const bf16x8*)(Kc + krow * 256 + ((t * 64 + kg * 16) ^ sw));
        #pragma unroll
        for (int t = 0; t < 4; ++t) {
          sc[j][0] = mfma16(kf[t], qf[0][t], sc[j][0]);
          sc[j][1] = mfma16(kf[t], qf[1][t], sc[j][1]);
        }
      }

      if (kt >= 2 * qb) {  // causal mask on diagonal tiles
        #pragma unroll
        for (int j = 0; j < 4; ++j) {
          const int kvb = kt * 64 + j * 16 + kg * 4;
          #pragma unroll
          for (int qs = 0; qs < 2; ++qs) {
            const int qq = q0w + qs * 16 + row16;
            #pragma unroll
            for (int r = 0; r < 4; ++r)
              if (kvb + r > qq) sc[j][qs][r] = -1e30f;
          }
        }
      }

      // ---- online softmax (exp2 domain), defer-max (THR=8)
      float pm[2], al[2] = {1.f, 1.f};
      #pragma unroll
      for (int qs = 0; qs < 2; ++qs) {
        float mx = fmaxf(fmaxf(hmax4(sc[0][qs]), hmax4(sc[1][qs])),
                         fmaxf(hmax4(sc[2][qs]), hmax4(sc[3][qs])));
        mx = fmaxf(mx, __shfl_xor(mx, 16, 64));
        mx = fmaxf(mx, __shfl_xor(mx, 32, 64));
        pm[qs] = mx;
      }
      const bool need = (pm[0] > m[0] + 8.f) || (pm[1] > m[1] + 8.f);
      if (__any(need)) {
        const float n0 = fmaxf(m[0], pm[0]), n1 = fmaxf(m[1], pm[1]);
        al[0] = exp2f(m[0] - n0); al[1] = exp2f(m[1] - n1);
        m[0] = n0; m[1] = n1;
        float aq[2][4];
        #pragma unroll
        for (int qs2 = 0; qs2 < 2; ++qs2)
          #pragma unroll
          for (int r = 0; r < 4; ++r)
            aq[qs2][r] = __shfl(al[qs2], kg * 4 + r, 64);
        #pragma unroll
        for (int qs2 = 0; qs2 < 2; ++qs2)
          #pragma unroll
          for (int dt = 0; dt < 8; ++dt)
            #pragma unroll
            for (int r = 0; r < 4; ++r)
              oacc[qs2][dt][r] *= aq[qs2][r];
      }

      // ---- P = exp2(S - m) -> per-wave LDS (bf16, swizzled), row-sum
      #pragma unroll
      for (int qs = 0; qs < 2; ++qs) {
        const int q = qs * 16 + row16;
        const int psw = (q & 7) << 4;
        float ps = 0.f;
        #pragma unroll
        for (int j = 0; j < 4; ++j) {
          const float p0 = exp2f(sc[j][qs][0] - m[qs]);
          const float p1 = exp2f(sc[j][qs][1] - m[qs]);
          const float p2 = exp2f(sc[j][qs][2] - m[qs]);
          const float p3 = exp2f(sc[j][qs][3] - m[qs]);
          ps += (p0 + p1) + (p2 + p3);
          uint2 pw; pw.x = pkbf(p0, p1); pw.y = pkbf(p2, p3);
          *(uint2*)(Pl + q * 128 + ((j * 32 + kg * 8) ^ psw)) = pw;
        }
        ps += __shfl_xor(ps, 16, 64);
        ps += __shfl_xor(ps, 32, 64);
        ls[qs] = ls[qs] * al[qs] + ps;
      }

      // ---- O += P V  (A = P rows q, B = Vt rows d)
      bf16x8 pa[2][2];
      #pragma unroll
      for (int qs2 = 0; qs2 < 2; ++qs2) {
        const int q = qs2 * 16 + row16;
        #pragma unroll
        for (int ks = 0; ks < 2; ++ks)
          pa[qs2][ks] = *(const bf16x8*)(Pl + q * 128 + ((ks * 64 + kg * 16) ^ ((q & 7) << 4)));
      }
      #pragma unroll
      for (int dt = 0; dt < 8; ++dt) {
        const int drow = dt * 16 + row16;
        const int vsw = (drow & 7) << 4;
        bf16x8 v0 = *(const bf16x8*)(Vc + drow * 128 + ((kg * 16) ^ vsw));
        bf16x8 v1 = *(const bf16x8*)(Vc + drow * 128 + ((64 + kg * 16) ^ vsw));
        oacc[0][dt] = mfma16(pa[0][0], v0, oacc[0][dt]);
        oacc[0][dt] = mfma16(pa[0][1], v1, oacc[0][dt]);
        oacc[1][dt] = mfma16(pa[1][0], v0, oacc[1][dt]);
        oacc[1][dt] = mfma16(pa[1][1], v1, oacc[1][dt]);
      }
    }

    __syncthreads();   // drains prefetch (vmcnt) + joins waves before buffer swap
    if (kt == last) break;
    cur ^= 1;
  }
#undef STAGE

  // ---- epilogue: normalize rows, write O[b*S + q][head*128 + d] bf16
  #pragma unroll
  for (int qs2 = 0; qs2 < 2; ++qs2) {
    #pragma unroll
    for (int r = 0; r < 4; ++r) {
      const float lr = __shfl(ls[qs2], kg * 4 + r, 64);
      const float inv = 1.0f / lr;
      const int q = q0w + qs2 * 16 + kg * 4 + r;
      const size_t orow = (size_t)(bidx * S_LEN + q) * HID + (size_t)head * DHEAD;
      #pragma unroll
      for (int dt = 0; dt < 8; ++dt)
        O[orow + dt * 16 + row16] = f2bf(oacc[qs2][dt][r] * inv);
    }
  }
}

extern "C" void kernel_launch(void* const* d_in, const int* in_sizes, int n_in,
                              void* d_out, int out_size, void* d_ws, size_t ws_size,
                              hipStream_t stream) {
  const float* x    = (const float*)d_in[0];
  const float* Wqkv = (const float*)d_in[1];
  const float* bqkv = (const float*)d_in[2];
  const float* Wout = (const float*)d_in[3];
  const float* bout = (const float*)d_in[4];
  float* out = (float*)d_out;

  if (ws_size < 100663296) return;  // insufficient scratch -> clean validation fail
  char* ws = (char*)d_ws;
  unsigned short* Qb    = (unsigned short*)(ws);
  unsigned short* Kb    = (unsigned short*)(ws + 16777216);
  unsigned short* Vtb   = (unsigned short*)(ws + 2 * 16777216);
  unsigned short* xb    = (unsigned short*)(ws + 3 * 16777216);
  unsigned short* Ob    = xb;  // alias: xb dead after QKV GEMM, Ob written after
  unsigned short* Wqkvb = (unsigned short*)(ws + 4 * 16777216);
  unsigned short* Woutb = (unsigned short*)(ws + 4 * 16777216 + 25165824);

  // x + Wqkv conversion in one launch; Wout conversion folded into attn_fwd.
  cvt_two<<<2048, 256, 0, stream>>>(x, xb, 4096 * 2048 / 4,
                                    Wqkv, Wqkvb, 6144 * 2048 / 4);

  gemm_qkv<<<dim3(32, 48), 256, 0, stream>>>(xb, Wqkvb, bqkv, Qb, Kb, Vtb);
  attn_fwd<<<dim3(16, 32), 256, 0, stream>>>(Qb, Kb, Vtb, Ob, Wout, Woutb);
  gemm_out<<<dim3(32, 16), 256, 0, stream>>>(Ob, Woutb, bout, out);
}